// Round 1
// baseline (787.629 us; speedup 1.0000x reference)
//
#include <hip/hip_runtime.h>
#include <hip/hip_bf16.h>
#include <math.h>

// Problem constants
#define NTOK   1024      // 2*512 tokens
#define DIMX   1024
#define INTERX 512
#define NEXP   16
#define RSCALE 2.5f

// ws layout (bytes). Total ~10.6 MB.
#define WS_COUNTS   0         // int[16]
#define WS_OFFSETS  128       // int[17]
#define WS_TOKIDX   256       // int[16*1024]
#define WS_TOKW     65792     // float[16*1024]
#define WS_H        131328    // float[5120*512]  (4096 routed rows + 1024 shared rows)

// ---------------------------------------------------------------------------
// Gating: scores = sigmoid(x @ gate_w.T); top-4 on (score + bias); weights
// from raw scores, normalized, * 2.5. Builds per-expert token lists.
// One wave per token.
// ---------------------------------------------------------------------------
__global__ void gate_topk(const float* __restrict__ x,
                          const float* __restrict__ gw,
                          const float* __restrict__ gb,
                          int* __restrict__ counts,
                          int* __restrict__ tok_idx,
                          float* __restrict__ tok_w)
{
    const int t = blockIdx.x;
    const int lane = threadIdx.x;   // 0..63
    float xv[16];
#pragma unroll
    for (int j = 0; j < 16; ++j) xv[j] = x[t * DIMX + j * 64 + lane];

    float sc[NEXP];
#pragma unroll 1
    for (int e = 0; e < NEXP; ++e) {
        const float* w = gw + e * DIMX;
        float acc = 0.f;
#pragma unroll
        for (int j = 0; j < 16; ++j) acc = fmaf(xv[j], w[j * 64 + lane], acc);
#pragma unroll
        for (int off = 32; off > 0; off >>= 1) acc += __shfl_xor(acc, off);
        sc[e] = acc;   // all lanes hold full dot after butterfly
    }

    if (lane == 0) {
        float s[NEXP], b[NEXP];
#pragma unroll
        for (int e = 0; e < NEXP; ++e) {
            float v = 1.f / (1.f + __expf(-sc[e]));
            s[e] = v;
            b[e] = v + gb[e];
        }
        int   idx[4];
        float wsel[4];
        unsigned used = 0;
#pragma unroll
        for (int k = 0; k < 4; ++k) {
            int best = 0; float bv = -1e30f;
#pragma unroll
            for (int e = 0; e < NEXP; ++e) {
                if (!((used >> e) & 1u) && b[e] > bv) { bv = b[e]; best = e; }
            }
            used |= 1u << best;
            idx[k] = best; wsel[k] = s[best];
        }
        float sum = wsel[0] + wsel[1] + wsel[2] + wsel[3];
        float scale = RSCALE / sum;
#pragma unroll
        for (int k = 0; k < 4; ++k) {
            int e = idx[k];
            int pos = atomicAdd(&counts[e], 1);
            tok_idx[e * NTOK + pos] = t;
            tok_w[e * NTOK + pos]   = wsel[k] * scale;
        }
    }
}

// Exclusive prefix over 16 counts -> row offsets into compact h buffer.
__global__ void prefix16(const int* __restrict__ counts, int* __restrict__ offsets)
{
    if (threadIdx.x == 0 && blockIdx.x == 0) {
        int off = 0;
        for (int e = 0; e < NEXP; ++e) { offsets[e] = off; off += counts[e]; }
        offsets[NEXP] = off;   // == 4096; shared-expert rows follow
    }
}

// ---------------------------------------------------------------------------
// Phase 1: for expert e (z), h-col chunk g0 (y), token tile m0 (x):
//   h[row, g0..g0+63] = silu(gate)*up of  x_gathered @ w13_e^T
// Tile 64 tokens x 128 pre-act cols (interleaved gate/up pairs), K-step 16.
// Block 256 threads, thread tile 4x8 fp32.
// ---------------------------------------------------------------------------
__global__ __launch_bounds__(256) void ffn1(
    const float* __restrict__ x,
    const float* __restrict__ w13,
    const float* __restrict__ w13s,
    const int* __restrict__ counts,
    const int* __restrict__ offsets,
    const int* __restrict__ tok_idx,
    float* __restrict__ h)
{
    const int e  = blockIdx.z;                       // 0..16 (16 == shared)
    const int Me = (e == NEXP) ? NTOK : counts[e];
    const int m0 = blockIdx.x * 64;
    if (m0 >= Me) return;
    const int g0 = blockIdx.y * 64;                  // h-column base
    const float* __restrict__ B = (e == NEXP) ? w13s
                                : (w13 + (size_t)e * (2 * INTERX) * DIMX);
    const int rowbase = (e == NEXP) ? offsets[NEXP] : offsets[e];

    const int tid = threadIdx.x;
    const int tx = tid & 15, ty = tid >> 4;
    const int am = tid & 63, aq = tid >> 6;          // A-stage: token am, k-quad aq
    const int c0 = tid & 127, q0 = tid >> 7;         // B-stage: col c0, k-quads q0 and q0+2

    int tokA = -1;
    if (m0 + am < Me) tokA = (e == NEXP) ? (m0 + am) : tok_idx[e * NTOK + m0 + am];

    // interleaved mapping: Bs col c -> w13 row (c even: gate g0+c/2, odd: up 512+g0+c/2)
    const int rB = (c0 & 1) ? (INTERX + g0 + (c0 >> 1)) : (g0 + (c0 >> 1));
    const float* pA  = (tokA >= 0) ? (x + (size_t)tokA * DIMX + aq * 4) : x;
    const float* pB0 = B + (size_t)rB * DIMX + q0 * 4;
    const float* pB1 = B + (size_t)rB * DIMX + (q0 + 2) * 4;

    __shared__ float As[16][64];
    __shared__ float Bs[16][128];
    float acc[4][8];
#pragma unroll
    for (int i = 0; i < 4; ++i)
#pragma unroll
        for (int j = 0; j < 8; ++j) acc[i][j] = 0.f;

    for (int k0 = 0; k0 < DIMX; k0 += 16) {
        float4 av = *(const float4*)(pA + k0);
        if (tokA < 0) av = make_float4(0.f, 0.f, 0.f, 0.f);
        const float4 b0 = *(const float4*)(pB0 + k0);
        const float4 b1 = *(const float4*)(pB1 + k0);
        __syncthreads();
        As[aq * 4 + 0][am] = av.x;
        As[aq * 4 + 1][am] = av.y;
        As[aq * 4 + 2][am] = av.z;
        As[aq * 4 + 3][am] = av.w;
        Bs[q0 * 4 + 0][c0] = b0.x; Bs[q0 * 4 + 1][c0] = b0.y;
        Bs[q0 * 4 + 2][c0] = b0.z; Bs[q0 * 4 + 3][c0] = b0.w;
        Bs[(q0 + 2) * 4 + 0][c0] = b1.x; Bs[(q0 + 2) * 4 + 1][c0] = b1.y;
        Bs[(q0 + 2) * 4 + 2][c0] = b1.z; Bs[(q0 + 2) * 4 + 3][c0] = b1.w;
        __syncthreads();
#pragma unroll
        for (int kk = 0; kk < 16; ++kk) {
            const float4 a  = *(const float4*)&As[kk][ty * 4];
            const float4 v0 = *(const float4*)&Bs[kk][tx * 8];
            const float4 v1 = *(const float4*)&Bs[kk][tx * 8 + 4];
            const float aa[4] = {a.x, a.y, a.z, a.w};
            const float bb[8] = {v0.x, v0.y, v0.z, v0.w, v1.x, v1.y, v1.z, v1.w};
#pragma unroll
            for (int i = 0; i < 4; ++i)
#pragma unroll
                for (int j = 0; j < 8; ++j)
                    acc[i][j] = fmaf(aa[i], bb[j], acc[i][j]);
        }
    }

    // epilogue: pairs (2*jp, 2*jp+1) = (gate, up) -> h col g0 + tx*4 + jp
#pragma unroll
    for (int i = 0; i < 4; ++i) {
        const int m = m0 + ty * 4 + i;
        if (m >= Me) continue;
        float vals[4];
#pragma unroll
        for (int jp = 0; jp < 4; ++jp) {
            const float g = acc[i][2 * jp], u = acc[i][2 * jp + 1];
            vals[jp] = g * u / (1.f + __expf(-g));
        }
        float* hp = h + (size_t)(rowbase + m) * INTERX + g0 + tx * 4;
        *(float4*)hp = make_float4(vals[0], vals[1], vals[2], vals[3]);
    }
}

// ---------------------------------------------------------------------------
// Phase 2: out[tok, n0..n0+127] (+)= w * (h_row @ w2_e^T)
// SHARED=true: plain store (initializes out). SHARED=false: atomicAdd.
// ---------------------------------------------------------------------------
template <bool SHARED>
__global__ __launch_bounds__(256) void ffn2(
    const float* __restrict__ w2,
    const float* __restrict__ w2s,
    const int* __restrict__ counts,
    const int* __restrict__ offsets,
    const int* __restrict__ tok_idx,
    const float* __restrict__ tok_w,
    const float* __restrict__ h,
    float* __restrict__ out)
{
    const int e  = SHARED ? NEXP : blockIdx.z;
    const int Me = SHARED ? NTOK : counts[e];
    const int m0 = blockIdx.x * 64;
    if (m0 >= Me) return;
    const int n0 = blockIdx.y * 128;
    const float* __restrict__ B = SHARED ? w2s : (w2 + (size_t)e * DIMX * INTERX);
    const int rowbase = SHARED ? offsets[NEXP] : offsets[e];

    const int tid = threadIdx.x;
    const int tx = tid & 15, ty = tid >> 4;
    const int am = tid & 63, aq = tid >> 6;
    const int c0 = tid & 127, q0 = tid >> 7;

    const float* pA  = h + (size_t)(rowbase + m0 + am) * INTERX + aq * 4;
    const float* pB0 = B + (size_t)(n0 + c0) * INTERX + q0 * 4;
    const float* pB1 = B + (size_t)(n0 + c0) * INTERX + (q0 + 2) * 4;

    __shared__ float As[16][64];
    __shared__ float Bs[16][128];
    float acc[4][8];
#pragma unroll
    for (int i = 0; i < 4; ++i)
#pragma unroll
        for (int j = 0; j < 8; ++j) acc[i][j] = 0.f;

    for (int k0 = 0; k0 < INTERX; k0 += 16) {
        const float4 av = *(const float4*)(pA + k0);
        const float4 b0 = *(const float4*)(pB0 + k0);
        const float4 b1 = *(const float4*)(pB1 + k0);
        __syncthreads();
        As[aq * 4 + 0][am] = av.x;
        As[aq * 4 + 1][am] = av.y;
        As[aq * 4 + 2][am] = av.z;
        As[aq * 4 + 3][am] = av.w;
        Bs[q0 * 4 + 0][c0] = b0.x; Bs[q0 * 4 + 1][c0] = b0.y;
        Bs[q0 * 4 + 2][c0] = b0.z; Bs[q0 * 4 + 3][c0] = b0.w;
        Bs[(q0 + 2) * 4 + 0][c0] = b1.x; Bs[(q0 + 2) * 4 + 1][c0] = b1.y;
        Bs[(q0 + 2) * 4 + 2][c0] = b1.z; Bs[(q0 + 2) * 4 + 3][c0] = b1.w;
        __syncthreads();
#pragma unroll
        for (int kk = 0; kk < 16; ++kk) {
            const float4 a  = *(const float4*)&As[kk][ty * 4];
            const float4 v0 = *(const float4*)&Bs[kk][tx * 8];
            const float4 v1 = *(const float4*)&Bs[kk][tx * 8 + 4];
            const float aa[4] = {a.x, a.y, a.z, a.w};
            const float bb[8] = {v0.x, v0.y, v0.z, v0.w, v1.x, v1.y, v1.z, v1.w};
#pragma unroll
            for (int i = 0; i < 4; ++i)
#pragma unroll
                for (int j = 0; j < 8; ++j)
                    acc[i][j] = fmaf(aa[i], bb[j], acc[i][j]);
        }
    }

#pragma unroll
    for (int i = 0; i < 4; ++i) {
        const int m = m0 + ty * 4 + i;
        if (m >= Me) continue;
        int tok; float wgt;
        if (SHARED) { tok = m; wgt = 1.f; }
        else { tok = tok_idx[e * NTOK + m]; wgt = tok_w[e * NTOK + m]; }
        float* op = out + (size_t)tok * DIMX + n0 + tx * 8;
        if (SHARED) {
#pragma unroll
            for (int j = 0; j < 8; ++j) op[j] = acc[i][j];
        } else {
#pragma unroll
            for (int j = 0; j < 8; ++j) atomicAdd(&op[j], wgt * acc[i][j]);
        }
    }
}

// ---------------------------------------------------------------------------
extern "C" void kernel_launch(void* const* d_in, const int* in_sizes, int n_in,
                              void* d_out, int out_size, void* d_ws, size_t ws_size,
                              hipStream_t stream)
{
    const float* x    = (const float*)d_in[0];
    // d_in[1] = input_ids (unused by the reference computation)
    const float* gw   = (const float*)d_in[2];
    const float* gb   = (const float*)d_in[3];
    const float* w13  = (const float*)d_in[4];
    const float* w2   = (const float*)d_in[5];
    const float* w13s = (const float*)d_in[6];
    const float* w2s  = (const float*)d_in[7];
    float* out = (float*)d_out;

    char* ws = (char*)d_ws;
    int*   counts  = (int*)(ws + WS_COUNTS);
    int*   offsets = (int*)(ws + WS_OFFSETS);
    int*   tok_idx = (int*)(ws + WS_TOKIDX);
    float* tok_w   = (float*)(ws + WS_TOKW);
    float* h       = (float*)(ws + WS_H);

    hipMemsetAsync(counts, 0, NEXP * sizeof(int), stream);
    gate_topk<<<NTOK, 64, 0, stream>>>(x, gw, gb, counts, tok_idx, tok_w);
    prefix16<<<1, 64, 0, stream>>>(counts, offsets);

    {   // phase 1: all 16 routed experts + shared (z == 16)
        dim3 g(16, 8, 17);
        ffn1<<<g, 256, 0, stream>>>(x, w13, w13s, counts, offsets, tok_idx, h);
    }
    {   // phase 2: shared first (plain store initializes out), then routed adds
        dim3 gs(16, 8, 1);
        ffn2<true><<<gs, 256, 0, stream>>>(w2, w2s, counts, offsets, tok_idx, tok_w, h, out);
        dim3 gr(16, 8, 16);
        ffn2<false><<<gr, 256, 0, stream>>>(w2, w2s, counts, offsets, tok_idx, tok_w, h, out);
    }
}

// Round 2
// 220.854 us; speedup vs baseline: 3.5663x; 3.5663x over previous
//
#include <hip/hip_runtime.h>
#include <hip/hip_bf16.h>
#include <math.h>

// Problem constants
#define NTOK   1024      // 2*512 tokens
#define DIMX   1024
#define INTERX 512
#define NEXP   16
#define RSCALE 2.5f

typedef _Float16 f16x8 __attribute__((ext_vector_type(8)));
typedef float    f32x4 __attribute__((ext_vector_type(4)));

// ws layout (bytes), total ~26.3 MB
#define WS_COUNTS   0                              // int[16]
#define WS_OFFSETS  128                            // int[17]
#define WS_TOKIDX   256                            // int[16*1024]
#define WS_SLOTS    (WS_TOKIDX + NEXP*NTOK*4)      // int[1024*4]   (e<<10 | pos)
#define WS_WQ       (WS_SLOTS + NTOK*4*4)          // float[1024*4] (route weights)
#define WS_H        (WS_WQ + NTOK*4*4)             // _Float16[5120*512]
#define WS_YC       (WS_H + 5120*512*2)            // float[5120*1024]

// ---------------------------------------------------------------------------
// Gating: scores = sigmoid(x @ gate_w.T); top-4 on (score + bias); weights
// from raw scores, normalized, * 2.5. One wave per token.
// ---------------------------------------------------------------------------
__global__ void gate_topk(const float* __restrict__ x,
                          const float* __restrict__ gw,
                          const float* __restrict__ gb,
                          int* __restrict__ counts,
                          int* __restrict__ tok_idx,
                          int* __restrict__ slots,
                          float* __restrict__ wq)
{
    const int t = blockIdx.x;
    const int lane = threadIdx.x;   // 0..63
    float xv[16];
#pragma unroll
    for (int j = 0; j < 16; ++j) xv[j] = x[t * DIMX + j * 64 + lane];

    float sc[NEXP];
#pragma unroll 1
    for (int e = 0; e < NEXP; ++e) {
        const float* w = gw + e * DIMX;
        float acc = 0.f;
#pragma unroll
        for (int j = 0; j < 16; ++j) acc = fmaf(xv[j], w[j * 64 + lane], acc);
#pragma unroll
        for (int off = 32; off > 0; off >>= 1) acc += __shfl_xor(acc, off);
        sc[e] = acc;
    }

    if (lane == 0) {
        float s[NEXP], b[NEXP];
#pragma unroll
        for (int e = 0; e < NEXP; ++e) {
            float v = 1.f / (1.f + __expf(-sc[e]));
            s[e] = v;
            b[e] = v + gb[e];
        }
        int   idx[4];
        float wsel[4];
        unsigned used = 0;
#pragma unroll
        for (int k = 0; k < 4; ++k) {
            int best = 0; float bv = -1e30f;
#pragma unroll
            for (int e = 0; e < NEXP; ++e) {
                if (!((used >> e) & 1u) && b[e] > bv) { bv = b[e]; best = e; }
            }
            used |= 1u << best;
            idx[k] = best; wsel[k] = s[best];
        }
        float sum = wsel[0] + wsel[1] + wsel[2] + wsel[3];
        float scale = RSCALE / sum;
#pragma unroll
        for (int k = 0; k < 4; ++k) {
            int e = idx[k];
            int pos = atomicAdd(&counts[e], 1);
            tok_idx[e * NTOK + pos] = t;
            slots[t * 4 + k] = (e << 10) | pos;
            wq[t * 4 + k] = wsel[k] * scale;
        }
    }
}

__global__ void prefix16(const int* __restrict__ counts, int* __restrict__ offsets)
{
    if (threadIdx.x == 0 && blockIdx.x == 0) {
        int off = 0;
        for (int e = 0; e < NEXP; ++e) { offsets[e] = off; off += counts[e]; }
        offsets[NEXP] = off;   // == 4096; shared-expert rows follow
    }
}

// ---------------------------------------------------------------------------
// FFN1 (MFMA): h[row, :64 cols] = silu(gate)*up of gathered x @ w13_e^T.
// Block 256 = 4 waves (2M x 2N). Block tile 64 tokens x 128 pre-act cols
// (= 64 h-cols: per wave, frag f in {0,1} gate / {2,3} up of same h-col).
// K-step 32, fp32->fp16 conversion during LDS staging.
// ---------------------------------------------------------------------------
__global__ __launch_bounds__(256) void ffn1(
    const float* __restrict__ x,
    const float* __restrict__ w13,
    const float* __restrict__ w13s,
    const int* __restrict__ counts,
    const int* __restrict__ offsets,
    const int* __restrict__ tok_idx,
    _Float16* __restrict__ h)
{
    const int e  = blockIdx.z;                      // 0..16 (16 == shared)
    const int Me = (e == NEXP) ? NTOK : counts[e];
    const int m0 = blockIdx.x * 64;
    if (m0 >= Me) return;
    const int g0 = blockIdx.y * 64;                 // h-column base (64 per block)
    const float* __restrict__ W = (e == NEXP) ? w13s
                                : (w13 + (size_t)e * (2 * INTERX) * DIMX);
    const int rowbase = (e == NEXP) ? offsets[NEXP] : offsets[e];

    const int tid  = threadIdx.x;
    const int lane = tid & 63;
    const int wid  = tid >> 6;
    const int wm   = wid >> 1, wn = wid & 1;

    // staging: thread covers row srow (A) / cols srow, srow+64 (B), k-chunk skc
    const int srow = tid >> 2;
    const int skc  = tid & 3;

    int mA = m0 + srow; if (mA >= Me) mA = m0;      // clamp (unused rows’ acc discarded)
    const int tokA = (e == NEXP) ? mA : tok_idx[e * NTOK + mA];
    const float* pA = x + (size_t)tokA * DIMX + skc * 8;

    // Bs col c -> w13 row: wave wn'=c>>6, c'=c&63; c'<32 gate, else up (+512)
    const int cA = srow, cB = srow + 64;
    const int rB0 = (cA & 63) < 32 ? (g0 + (cA >> 6) * 32 + (cA & 31))
                                   : (INTERX + g0 + (cA >> 6) * 32 + (cA & 31));
    const int rB1 = (cB & 63) < 32 ? (g0 + (cB >> 6) * 32 + (cB & 31))
                                   : (INTERX + g0 + (cB >> 6) * 32 + (cB & 31));
    const float* pB0 = W + (size_t)rB0 * DIMX + skc * 8;
    const float* pB1 = W + (size_t)rB1 * DIMX + skc * 8;

    __shared__ _Float16 As[64][40];     // 80B row stride: 16B-aligned, 2-way banks
    __shared__ _Float16 Bs[128][40];

    f32x4 acc[2][4];
#pragma unroll
    for (int mi = 0; mi < 2; ++mi)
#pragma unroll
        for (int f = 0; f < 4; ++f) acc[mi][f] = (f32x4){0.f, 0.f, 0.f, 0.f};

    const int rdA = wm * 32 + (lane & 15);
    const int rdB = wn * 64 + (lane & 15);
    const int rdk = (lane >> 4) * 8;

    for (int k0 = 0; k0 < DIMX; k0 += 32) {
        const float4 a0 = *(const float4*)(pA + k0);
        const float4 a1 = *(const float4*)(pA + k0 + 4);
        const float4 b00 = *(const float4*)(pB0 + k0);
        const float4 b01 = *(const float4*)(pB0 + k0 + 4);
        const float4 b10 = *(const float4*)(pB1 + k0);
        const float4 b11 = *(const float4*)(pB1 + k0 + 4);
        f16x8 av  = {(_Float16)a0.x, (_Float16)a0.y, (_Float16)a0.z, (_Float16)a0.w,
                     (_Float16)a1.x, (_Float16)a1.y, (_Float16)a1.z, (_Float16)a1.w};
        f16x8 bv0 = {(_Float16)b00.x, (_Float16)b00.y, (_Float16)b00.z, (_Float16)b00.w,
                     (_Float16)b01.x, (_Float16)b01.y, (_Float16)b01.z, (_Float16)b01.w};
        f16x8 bv1 = {(_Float16)b10.x, (_Float16)b10.y, (_Float16)b10.z, (_Float16)b10.w,
                     (_Float16)b11.x, (_Float16)b11.y, (_Float16)b11.z, (_Float16)b11.w};
        __syncthreads();
        *(f16x8*)&As[srow][skc * 8] = av;
        *(f16x8*)&Bs[cA][skc * 8]   = bv0;
        *(f16x8*)&Bs[cB][skc * 8]   = bv1;
        __syncthreads();

        f16x8 afr[2], bfr[4];
#pragma unroll
        for (int mi = 0; mi < 2; ++mi)
            afr[mi] = *(const f16x8*)&As[rdA + mi * 16][rdk];
#pragma unroll
        for (int f = 0; f < 4; ++f)
            bfr[f] = *(const f16x8*)&Bs[rdB + f * 16 - (lane & 15) + (lane & 15)][rdk];
#pragma unroll
        for (int mi = 0; mi < 2; ++mi)
#pragma unroll
            for (int f = 0; f < 4; ++f)
                acc[mi][f] = __builtin_amdgcn_mfma_f32_16x16x32_f16(
                    afr[mi], bfr[f], acc[mi][f], 0, 0, 0);
    }

    // epilogue: frag f (gate) pairs with frag f+2 (up), same lane -> same h-col
#pragma unroll
    for (int mi = 0; mi < 2; ++mi) {
#pragma unroll
        for (int r = 0; r < 4; ++r) {
            const int m = m0 + wm * 32 + mi * 16 + (lane >> 4) * 4 + r;
            if (m >= Me) continue;
#pragma unroll
            for (int f = 0; f < 2; ++f) {
                const float g = acc[mi][f][r];
                const float u = acc[mi][f + 2][r];
                const float hv = g * u / (1.f + __expf(-g));
                const int hc = g0 + wn * 32 + f * 16 + (lane & 15);
                h[(size_t)(rowbase + m) * INTERX + hc] = (_Float16)hv;
            }
        }
    }
}

// ---------------------------------------------------------------------------
// FFN2 (MFMA): yc[row, n0..n0+127] = h_row @ w2_e^T  (weights applied later).
// Same 4-wave structure; A already fp16, B converted during staging. K=512.
// ---------------------------------------------------------------------------
__global__ __launch_bounds__(256) void ffn2(
    const float* __restrict__ w2,
    const float* __restrict__ w2s,
    const int* __restrict__ counts,
    const int* __restrict__ offsets,
    const _Float16* __restrict__ h,
    float* __restrict__ yc)
{
    const int e  = blockIdx.z;
    const int Me = (e == NEXP) ? NTOK : counts[e];
    const int m0 = blockIdx.x * 64;
    if (m0 >= Me) return;
    const int n0 = blockIdx.y * 128;
    const float* __restrict__ W = (e == NEXP) ? w2s : (w2 + (size_t)e * DIMX * INTERX);
    const int rowbase = (e == NEXP) ? offsets[NEXP] : offsets[e];

    const int tid  = threadIdx.x;
    const int lane = tid & 63;
    const int wid  = tid >> 6;
    const int wm   = wid >> 1, wn = wid & 1;

    const int srow = tid >> 2;
    const int skc  = tid & 3;

    const _Float16* pA = h + (size_t)(rowbase + m0 + srow) * INTERX + skc * 8;
    const float* pB0 = W + (size_t)(n0 + srow) * INTERX + skc * 8;
    const float* pB1 = W + (size_t)(n0 + srow + 64) * INTERX + skc * 8;

    __shared__ _Float16 As[64][40];
    __shared__ _Float16 Bs[128][40];

    f32x4 acc[2][4];
#pragma unroll
    for (int mi = 0; mi < 2; ++mi)
#pragma unroll
        for (int f = 0; f < 4; ++f) acc[mi][f] = (f32x4){0.f, 0.f, 0.f, 0.f};

    const int rdA = wm * 32 + (lane & 15);
    const int rdB = wn * 64 + (lane & 15);
    const int rdk = (lane >> 4) * 8;

    for (int k0 = 0; k0 < INTERX; k0 += 32) {
        const f16x8  av  = *(const f16x8*)(pA + k0);
        const float4 b00 = *(const float4*)(pB0 + k0);
        const float4 b01 = *(const float4*)(pB0 + k0 + 4);
        const float4 b10 = *(const float4*)(pB1 + k0);
        const float4 b11 = *(const float4*)(pB1 + k0 + 4);
        f16x8 bv0 = {(_Float16)b00.x, (_Float16)b00.y, (_Float16)b00.z, (_Float16)b00.w,
                     (_Float16)b01.x, (_Float16)b01.y, (_Float16)b01.z, (_Float16)b01.w};
        f16x8 bv1 = {(_Float16)b10.x, (_Float16)b10.y, (_Float16)b10.z, (_Float16)b10.w,
                     (_Float16)b11.x, (_Float16)b11.y, (_Float16)b11.z, (_Float16)b11.w};
        __syncthreads();
        *(f16x8*)&As[srow][skc * 8]      = av;
        *(f16x8*)&Bs[srow][skc * 8]      = bv0;
        *(f16x8*)&Bs[srow + 64][skc * 8] = bv1;
        __syncthreads();

        f16x8 afr[2], bfr[4];
#pragma unroll
        for (int mi = 0; mi < 2; ++mi)
            afr[mi] = *(const f16x8*)&As[rdA + mi * 16][rdk];
#pragma unroll
        for (int f = 0; f < 4; ++f)
            bfr[f] = *(const f16x8*)&Bs[rdB + f * 16][rdk];
#pragma unroll
        for (int mi = 0; mi < 2; ++mi)
#pragma unroll
            for (int f = 0; f < 4; ++f)
                acc[mi][f] = __builtin_amdgcn_mfma_f32_16x16x32_f16(
                    afr[mi], bfr[f], acc[mi][f], 0, 0, 0);
    }

#pragma unroll
    for (int mi = 0; mi < 2; ++mi) {
#pragma unroll
        for (int r = 0; r < 4; ++r) {
            const int m = m0 + wm * 32 + mi * 16 + (lane >> 4) * 4 + r;
            if (m >= Me) continue;
            float* yp = yc + (size_t)(rowbase + m) * DIMX + n0 + wn * 64 + (lane & 15);
#pragma unroll
            for (int f = 0; f < 4; ++f)
                yp[f * 16] = acc[mi][f][r];
        }
    }
}

// ---------------------------------------------------------------------------
// Combine: out[t,:] = yc[shared_row(t),:] + sum_k wq[t,k] * yc[row(t,k),:]
// ---------------------------------------------------------------------------
__global__ __launch_bounds__(256) void combine(
    const int* __restrict__ offsets,
    const int* __restrict__ slots,
    const float* __restrict__ wq,
    const float* __restrict__ yc,
    float* __restrict__ out)
{
    const int t = blockIdx.x;
    const int tid = threadIdx.x;                 // 256 threads x float4 = 1024 cols
    const float4* ycv = (const float4*)yc;
    float4 a = ycv[(size_t)(offsets[NEXP] + t) * 256 + tid];
#pragma unroll
    for (int k = 0; k < 4; ++k) {
        const int s   = slots[t * 4 + k];
        const int e   = s >> 10, pos = s & 1023;
        const float w = wq[t * 4 + k];
        const float4 v = ycv[(size_t)(offsets[e] + pos) * 256 + tid];
        a.x = fmaf(w, v.x, a.x); a.y = fmaf(w, v.y, a.y);
        a.z = fmaf(w, v.z, a.z); a.w = fmaf(w, v.w, a.w);
    }
    ((float4*)out)[(size_t)t * 256 + tid] = a;
}

// ---------------------------------------------------------------------------
extern "C" void kernel_launch(void* const* d_in, const int* in_sizes, int n_in,
                              void* d_out, int out_size, void* d_ws, size_t ws_size,
                              hipStream_t stream)
{
    const float* x    = (const float*)d_in[0];
    // d_in[1] = input_ids (unused)
    const float* gw   = (const float*)d_in[2];
    const float* gb   = (const float*)d_in[3];
    const float* w13  = (const float*)d_in[4];
    const float* w2   = (const float*)d_in[5];
    const float* w13s = (const float*)d_in[6];
    const float* w2s  = (const float*)d_in[7];
    float* out = (float*)d_out;

    char* ws = (char*)d_ws;
    int*       counts  = (int*)(ws + WS_COUNTS);
    int*       offsets = (int*)(ws + WS_OFFSETS);
    int*       tok_idx = (int*)(ws + WS_TOKIDX);
    int*       slots   = (int*)(ws + WS_SLOTS);
    float*     wq      = (float*)(ws + WS_WQ);
    _Float16*  h       = (_Float16*)(ws + WS_H);
    float*     yc      = (float*)(ws + WS_YC);

    hipMemsetAsync(counts, 0, NEXP * sizeof(int), stream);
    gate_topk<<<NTOK, 64, 0, stream>>>(x, gw, gb, counts, tok_idx, slots, wq);
    prefix16<<<1, 64, 0, stream>>>(counts, offsets);

    {   // FFN1: 16 routed experts + shared (z == 16)
        dim3 g(16, 8, 17);
        ffn1<<<g, 256, 0, stream>>>(x, w13, w13s, counts, offsets, tok_idx, h);
    }
    {   // FFN2: all experts write compact yc (no atomics)
        dim3 g(16, 8, 17);
        ffn2<<<g, 256, 0, stream>>>(w2, w2s, counts, offsets, h, yc);
    }
    combine<<<NTOK, 256, 0, stream>>>(offsets, slots, wq, yc, out);
}